// Round 2
// baseline (110.948 us; speedup 1.0000x reference)
//
#include <hip/hip_runtime.h>
#include <float.h>
#include <limits.h>

#define DECAY 0.7f
#define THETA 1.0f
#define KWIN 5
#define GAIN_UP 1.5f
#define GAIN_DOWN 0.6f

// ---------- zero the counts array (vectorized, replaces slow runtime fill) ----------
__global__ void zero_counts(int* __restrict__ counts, int n) {
    int i = (blockIdx.x * blockDim.x + threadIdx.x) * 4;
    if (i + 3 < n) {
        *(int4*)(counts + i) = make_int4(0, 0, 0, 0);
    } else {
        for (int j = i; j < n; ++j) counts[j] = 0;
    }
}

// ---------- histogram of token ids (int4 loads, 4 atomics/thread) ----------
__global__ void hist_kernel(const int* __restrict__ tok, int n, int vocab,
                            int* __restrict__ counts) {
    int i = (blockIdx.x * blockDim.x + threadIdx.x) * 4;
    if (i + 3 < n) {
        int4 t4 = *(const int4*)(tok + i);
        int t;
        t = min(max(t4.x, 0), vocab - 1); atomicAdd(&counts[t], 1);
        t = min(max(t4.y, 0), vocab - 1); atomicAdd(&counts[t], 1);
        t = min(max(t4.z, 0), vocab - 1); atomicAdd(&counts[t], 1);
        t = min(max(t4.w, 0), vocab - 1); atomicAdd(&counts[t], 1);
    } else {
        for (int j = i; j < n; ++j) {
            int t = min(max(tok[j], 0), vocab - 1);
            atomicAdd(&counts[t], 1);
        }
    }
}

// Replay the LIF recurrence: matches reference fp32 arithmetic (no fma contraction).
__device__ __forceinline__ void lif_replay(float v0, int n, float& v_out, int& spikes_out) {
    float v = v0;
    int s = 0;
    for (int i = 0; i < n; ++i) {
        float vn = __fadd_rn(__fmul_rn(DECAY, v), 1.0f);
        if (vn >= THETA) { v = __fsub_rn(vn, THETA); ++s; }
        else             { v = vn; }
    }
    v_out = v;
    spikes_out = s;
}

// (larger v) then (smaller index) wins — matches lax.top_k stable tie-break.
__device__ __forceinline__ void better(float& bv, int& bi, float ov, int oi) {
    if (ov > bv || (ov == bv && oi < bi)) { bv = ov; bi = oi; }
}

// ---------- gains + per-wave top-5, zero barriers, zero LDS ----------
// Each wave owns a contiguous 256-entry slice; each lane owns 4 entries
// (lane + k*64). 5 rounds of 64-lane butterfly max-reduce emit 5 unique
// (value,index) candidates per wave.
__global__ void gains_top5(const int* __restrict__ counts,
                           const float* __restrict__ v0,
                           int vocab,
                           float* __restrict__ out,
                           float* __restrict__ cand_v,
                           int* __restrict__ cand_i) {
    int gid  = blockIdx.x * blockDim.x + threadIdx.x;
    int wave = gid >> 6;
    int lane = gid & 63;
    int base = wave * 256;

    float lv[4];
    int   li[4];
    #pragma unroll
    for (int k = 0; k < 4; ++k) {
        int idx = base + k * 64 + lane;
        float vf = -FLT_MAX;
        int   id = -1;
        if (idx < vocab) {
            int c = counts[idx];
            int s;
            lif_replay(v0[idx], c, vf, s);
            out[idx] = (s > 0) ? GAIN_DOWN : 1.0f;
            id = idx;
        }
        lv[k] = vf;
        li[k] = id;
    }

    #pragma unroll
    for (int r = 0; r < KWIN; ++r) {
        float bv = -FLT_MAX;
        int   bi = INT_MAX;
        #pragma unroll
        for (int k = 0; k < 4; ++k) {
            if (li[k] >= 0) better(bv, bi, lv[k], li[k]);
        }
        #pragma unroll
        for (int off = 32; off > 0; off >>= 1) {
            float ov = __shfl_xor(bv, off, 64);
            int   oi = __shfl_xor(bi, off, 64);
            better(bv, bi, ov, oi);
        }
        if (lane == 0) {
            cand_v[wave * KWIN + r] = bv;
            cand_i[wave * KWIN + r] = bi;
        }
        #pragma unroll
        for (int k = 0; k < 4; ++k) {
            if (li[k] == bi) li[k] = -1;   // winner out of next rounds
        }
    }
}

// ---------- single-wave merge of all candidates, zero barriers ----------
// Candidate indices are globally unique, so exclusion = "not already a winner".
__global__ void merge_top5(const float* __restrict__ cand_v,
                           const int* __restrict__ cand_i,
                           int n_cand,
                           float* __restrict__ out) {
    int lane = threadIdx.x;   // launched with 64 threads
    int winners[KWIN];
    #pragma unroll
    for (int r = 0; r < KWIN; ++r) winners[r] = -1;

    #pragma unroll
    for (int r = 0; r < KWIN; ++r) {
        float bv = -FLT_MAX;
        int   bi = INT_MAX;
        for (int j = lane; j < n_cand; j += 64) {
            int ci = cand_i[j];
            bool excl = false;
            #pragma unroll
            for (int q = 0; q < KWIN; ++q) {
                if (q < r && winners[q] == ci) excl = true;
            }
            if (excl) continue;
            better(bv, bi, cand_v[j], ci);
        }
        #pragma unroll
        for (int off = 32; off > 0; off >>= 1) {
            float ov = __shfl_xor(bv, off, 64);
            int   oi = __shfl_xor(bi, off, 64);
            better(bv, bi, ov, oi);
        }
        winners[r] = bi;      // every lane tracks all winners
    }

    if (lane < KWIN) {
        int w = winners[lane];
        if (w >= 0 && w != INT_MAX) out[w] = GAIN_UP;
    }
}

extern "C" void kernel_launch(void* const* d_in, const int* in_sizes, int n_in,
                              void* d_out, int out_size, void* d_ws, size_t ws_size,
                              hipStream_t stream) {
    const int*   tok = (const int*)d_in[0];
    const float* v0  = (const float*)d_in[1];
    int n     = in_sizes[0];      // 8192
    int vocab = in_sizes[1];      // 128000
    float* out = (float*)d_out;

    int nwaves = (vocab + 255) / 256;          // candidate-producing waves
    int gblocks = (vocab + 1023) / 1024;       // 256 thr × 4 elem = 1024/block

    // ws: counts[vocab] i32 | cand_v[nwaves*5] f32 | cand_i[nwaves*5] i32
    int*   counts = (int*)d_ws;
    float* cand_v = (float*)((char*)d_ws + (size_t)vocab * sizeof(int));
    int*   cand_i = (int*)(cand_v + (size_t)nwaves * KWIN);

    zero_counts<<<(vocab / 4 + 255) / 256 + 1, 256, 0, stream>>>(counts, vocab);
    hist_kernel<<<(n / 4 + 255) / 256 + 1, 256, 0, stream>>>(tok, n, vocab, counts);
    gains_top5<<<gblocks, 256, 0, stream>>>(counts, v0, vocab, out, cand_v, cand_i);
    merge_top5<<<1, 64, 0, stream>>>(cand_v, cand_i, nwaves * KWIN, out);
}

// Round 7
// 74.958 us; speedup vs baseline: 1.4801x; 1.4801x over previous
//
#include <hip/hip_runtime.h>
#include <float.h>
#include <limits.h>

#define DECAY 0.7f
#define THETA 1.0f
#define KWIN 5
#define GAIN_UP 1.5f
#define GAIN_DOWN 0.6f

// ---------- zero the counts array (vectorized, replaces slow runtime fill) ----------
__global__ void zero_counts(int* __restrict__ counts, int n) {
    int i = (blockIdx.x * blockDim.x + threadIdx.x) * 4;
    if (i + 3 < n) {
        *(int4*)(counts + i) = make_int4(0, 0, 0, 0);
    } else {
        for (int j = i; j < n; ++j) counts[j] = 0;
    }
}

// ---------- histogram of token ids (int4 loads, 4 atomics/thread) ----------
__global__ void hist_kernel(const int* __restrict__ tok, int n, int vocab,
                            int* __restrict__ counts) {
    int i = (blockIdx.x * blockDim.x + threadIdx.x) * 4;
    if (i + 3 < n) {
        int4 t4 = *(const int4*)(tok + i);
        int t;
        t = min(max(t4.x, 0), vocab - 1); atomicAdd(&counts[t], 1);
        t = min(max(t4.y, 0), vocab - 1); atomicAdd(&counts[t], 1);
        t = min(max(t4.z, 0), vocab - 1); atomicAdd(&counts[t], 1);
        t = min(max(t4.w, 0), vocab - 1); atomicAdd(&counts[t], 1);
    } else {
        for (int j = i; j < n; ++j) {
            int t = min(max(tok[j], 0), vocab - 1);
            atomicAdd(&counts[t], 1);
        }
    }
}

// Replay the LIF recurrence: matches reference fp32 arithmetic (no fma contraction).
__device__ __forceinline__ void lif_replay(float v0, int n, float& v_out, int& spikes_out) {
    float v = v0;
    int s = 0;
    for (int i = 0; i < n; ++i) {
        float vn = __fadd_rn(__fmul_rn(DECAY, v), 1.0f);
        if (vn >= THETA) { v = __fsub_rn(vn, THETA); ++s; }
        else             { v = vn; }
    }
    v_out = v;
    spikes_out = s;
}

// (larger v) then (smaller index) wins — matches lax.top_k stable tie-break.
__device__ __forceinline__ void better(float& bv, int& bi, float ov, int oi) {
    if (ov > bv || (ov == bv && oi < bi)) { bv = ov; bi = oi; }
}

// ---------- gains + per-wave top-5, zero barriers, zero LDS ----------
// Each wave owns a contiguous 256-entry slice; each lane owns 4 entries
// (lane + k*64). 5 rounds of 64-lane butterfly max-reduce emit 5 unique
// (value,index) candidates per wave.
__global__ void gains_top5(const int* __restrict__ counts,
                           const float* __restrict__ v0,
                           int vocab,
                           float* __restrict__ out,
                           float* __restrict__ cand_v,
                           int* __restrict__ cand_i) {
    int gid  = blockIdx.x * blockDim.x + threadIdx.x;
    int wave = gid >> 6;
    int lane = gid & 63;
    int base = wave * 256;

    float lv[4];
    int   li[4];
    #pragma unroll
    for (int k = 0; k < 4; ++k) {
        int idx = base + k * 64 + lane;
        float vf = -FLT_MAX;
        int   id = -1;
        if (idx < vocab) {
            int c = counts[idx];
            int s;
            lif_replay(v0[idx], c, vf, s);
            out[idx] = (s > 0) ? GAIN_DOWN : 1.0f;
            id = idx;
        }
        lv[k] = vf;
        li[k] = id;
    }

    #pragma unroll
    for (int r = 0; r < KWIN; ++r) {
        float bv = -FLT_MAX;
        int   bi = INT_MAX;
        #pragma unroll
        for (int k = 0; k < 4; ++k) {
            if (li[k] >= 0) better(bv, bi, lv[k], li[k]);
        }
        #pragma unroll
        for (int off = 32; off > 0; off >>= 1) {
            float ov = __shfl_xor(bv, off, 64);
            int   oi = __shfl_xor(bi, off, 64);
            better(bv, bi, ov, oi);
        }
        if (lane == 0) {
            cand_v[wave * KWIN + r] = bv;
            cand_i[wave * KWIN + r] = bi;
        }
        #pragma unroll
        for (int k = 0; k < 4; ++k) {
            if (li[k] == bi) li[k] = -1;   // winner out of next rounds
        }
    }
}

// ---------- single-pass merge via strictly-ordered u64 keys ----------
// key = sortable(v)<<32 | ~index  ->  max key == (largest v, then smallest
// index), exactly the lax.top_k tie-break. Indices are globally unique so
// keys are strictly ordered: round-r exclusion is simply key < winner[r-1].
// Each thread loads its <=3 candidates into registers ONCE; 5 rounds of
// filtered butterfly max. No register-array indexing anywhere.
#define MAXC 8   // supports up to 8*256 = 2048 candidates (we have 625)

__global__ void merge_top5(const float* __restrict__ cand_v,
                           const int* __restrict__ cand_i,
                           int n_cand,
                           float* __restrict__ out) {
    __shared__ unsigned long long swk[4];   // per-wave round winner

    const int tid  = threadIdx.x;           // 256 threads
    const int wave = tid >> 6;
    const int lane = tid & 63;

    // Load candidates -> sortable keys (0 = empty sentinel, below all real keys
    // since real values have sortable(v) != 0 or nonzero index bits).
    unsigned long long k0 = 0ULL, k1 = 0ULL, k2 = 0ULL, k3 = 0ULL;
    unsigned long long k4 = 0ULL, k5 = 0ULL, k6 = 0ULL, k7 = 0ULL;
    #pragma unroll
    for (int s = 0; s < MAXC; ++s) {
        int j = s * 256 + tid;
        unsigned long long key = 0ULL;
        if (j < n_cand) {
            int ci = cand_i[j];
            if (ci >= 0 && ci != INT_MAX) {
                unsigned b  = __float_as_uint(cand_v[j]);
                unsigned sv = (b & 0x80000000u) ? ~b : (b | 0x80000000u);
                key = ((unsigned long long)sv << 32) | (unsigned)(~(unsigned)ci);
            }
        }
        if (s == 0) k0 = key; else if (s == 1) k1 = key;
        else if (s == 2) k2 = key; else if (s == 3) k3 = key;
        else if (s == 4) k4 = key; else if (s == 5) k5 = key;
        else if (s == 6) k6 = key; else k7 = key;
    }

    unsigned long long thresh = ~0ULL;      // round 0: everything participates
    for (int r = 0; r < KWIN; ++r) {
        unsigned long long best = 0ULL;
        if (k0 < thresh && k0 > best) best = k0;
        if (k1 < thresh && k1 > best) best = k1;
        if (k2 < thresh && k2 > best) best = k2;
        if (k3 < thresh && k3 > best) best = k3;
        if (k4 < thresh && k4 > best) best = k4;
        if (k5 < thresh && k5 > best) best = k5;
        if (k6 < thresh && k6 > best) best = k6;
        if (k7 < thresh && k7 > best) best = k7;

        // 64-lane butterfly max (u64 via two 32-bit shuffles)
        #pragma unroll
        for (int off = 32; off > 0; off >>= 1) {
            unsigned hi = (unsigned)(best >> 32);
            unsigned lo = (unsigned)(best & 0xFFFFFFFFu);
            unsigned ohi = __shfl_xor(hi, off, 64);
            unsigned olo = __shfl_xor(lo, off, 64);
            unsigned long long ok = ((unsigned long long)ohi << 32) | olo;
            if (ok > best) best = ok;
        }
        if (lane == 0) swk[wave] = best;
        __syncthreads();

        unsigned long long bb = swk[0];
        if (swk[1] > bb) bb = swk[1];
        if (swk[2] > bb) bb = swk[2];
        if (swk[3] > bb) bb = swk[3];
        __syncthreads();                    // swk reused next round

        if (tid == 0 && bb != 0ULL) {
            unsigned inv = (unsigned)(bb & 0xFFFFFFFFu);
            int idx = (int)(~inv);
            out[idx] = GAIN_UP;
        }
        thresh = bb;                        // next round: strictly below this
    }
}

extern "C" void kernel_launch(void* const* d_in, const int* in_sizes, int n_in,
                              void* d_out, int out_size, void* d_ws, size_t ws_size,
                              hipStream_t stream) {
    const int*   tok = (const int*)d_in[0];
    const float* v0  = (const float*)d_in[1];
    int n     = in_sizes[0];      // 8192
    int vocab = in_sizes[1];      // 128000
    float* out = (float*)d_out;

    int nwaves = (vocab + 255) / 256;          // candidate-producing waves
    int gblocks = (vocab + 1023) / 1024;       // 256 thr × 4 elem = 1024/block

    // ws: counts[vocab] i32 | cand_v[nwaves*5] f32 | cand_i[nwaves*5] i32
    int*   counts = (int*)d_ws;
    float* cand_v = (float*)((char*)d_ws + (size_t)vocab * sizeof(int));
    int*   cand_i = (int*)(cand_v + (size_t)nwaves * KWIN);

    zero_counts<<<(vocab / 4 + 255) / 256 + 1, 256, 0, stream>>>(counts, vocab);
    hist_kernel<<<(n / 4 + 255) / 256 + 1, 256, 0, stream>>>(tok, n, vocab, counts);
    gains_top5<<<gblocks, 256, 0, stream>>>(counts, v0, vocab, out, cand_v, cand_i);
    merge_top5<<<1, 256, 0, stream>>>(cand_v, cand_i, nwaves * KWIN, out);
}

// Round 8
// 74.239 us; speedup vs baseline: 1.4945x; 1.0097x over previous
//
#include <hip/hip_runtime.h>
#include <float.h>
#include <limits.h>

#define DECAY 0.7f
#define THETA 1.0f
#define KWIN 5
#define GAIN_UP 1.5f
#define GAIN_DOWN 0.6f

#define NT 256
#define SLICE 1024          // vocab entries per block (4 per thread)

// Replay the LIF recurrence: matches reference fp32 arithmetic (no fma contraction).
__device__ __forceinline__ void lif_replay(float v0, int n, float& v_out, int& spikes_out) {
    float v = v0;
    int s = 0;
    for (int i = 0; i < n; ++i) {
        float vn = __fadd_rn(__fmul_rn(DECAY, v), 1.0f);
        if (vn >= THETA) { v = __fsub_rn(vn, THETA); ++s; }
        else             { v = vn; }
    }
    v_out = v;
    spikes_out = s;
}

// (larger v) then (smaller index) wins — matches lax.top_k stable tie-break.
__device__ __forceinline__ void better(float& bv, int& bi, float ov, int oi) {
    if (ov > bv || (ov == bv && oi < bi)) { bv = ov; bi = oi; }
}

// ---------- dispatch 1: LDS slice-histogram -> gains -> per-wave top-5 ----------
// Each block owns a 1024-entry vocab slice and histograms it by scanning ALL
// tokens (125x redundant = 4 MB, L2-resident). This removes the zero+hist
// dispatches and every inter-block dependency. The gains/top-5 phases are
// R1's proven gains_top5 pattern, reading counts from LDS instead of global.
__global__ void fused_local(const int* __restrict__ tok,
                            const float* __restrict__ v0,
                            int n, int vocab,
                            float* __restrict__ out,
                            float* __restrict__ cand_v,
                            int* __restrict__ cand_i) {
    __shared__ int hist[SLICE];

    const int tid  = threadIdx.x;
    const int bid  = blockIdx.x;
    const int wave = tid >> 6;
    const int lane = tid & 63;
    const int sbase = bid * SLICE;

    // Phase A: zero LDS histogram
    #pragma unroll
    for (int k = 0; k < SLICE / NT; ++k) {
        hist[k * NT + tid] = 0;
    }
    __syncthreads();

    // Phase B: histogram my slice by scanning all tokens (int4 loads)
    int nv4 = n & ~3;
    for (int j = tid * 4; j < nv4; j += NT * 4) {
        int4 t4 = *(const int4*)(tok + j);
        int t; unsigned r;
        t = min(max(t4.x, 0), vocab - 1); r = (unsigned)(t - sbase); if (r < SLICE) atomicAdd(&hist[r], 1);
        t = min(max(t4.y, 0), vocab - 1); r = (unsigned)(t - sbase); if (r < SLICE) atomicAdd(&hist[r], 1);
        t = min(max(t4.z, 0), vocab - 1); r = (unsigned)(t - sbase); if (r < SLICE) atomicAdd(&hist[r], 1);
        t = min(max(t4.w, 0), vocab - 1); r = (unsigned)(t - sbase); if (r < SLICE) atomicAdd(&hist[r], 1);
    }
    for (int j = nv4 + tid; j < n; j += NT) {
        int t = min(max(tok[j], 0), vocab - 1);
        unsigned r = (unsigned)(t - sbase);
        if (r < SLICE) atomicAdd(&hist[r], 1);
    }
    __syncthreads();

    // Phase C: gains + per-wave top-5 (R1's proven pattern; counts from LDS).
    // Wave w owns slice rows [w*256, w*256+256); lane handles 4 entries.
    const int wbase = wave * 256;            // offset within slice
    float lv[4];
    int   li[4];
    #pragma unroll
    for (int k = 0; k < 4; ++k) {
        int off = wbase + k * 64 + lane;     // 0..1023 within slice
        int idx = sbase + off;               // global vocab index
        float vf = -FLT_MAX;
        int   id = -1;
        if (idx < vocab) {
            int c = hist[off];
            int s;
            lif_replay(v0[idx], c, vf, s);
            out[idx] = (s > 0) ? GAIN_DOWN : 1.0f;
            id = idx;
        }
        lv[k] = vf;
        li[k] = id;
    }

    const int gw = bid * (NT / 64) + wave;   // global wave id (candidate slot)
    #pragma unroll
    for (int r = 0; r < KWIN; ++r) {
        float bv = -FLT_MAX;
        int   bi = INT_MAX;
        #pragma unroll
        for (int k = 0; k < 4; ++k) {
            if (li[k] >= 0) better(bv, bi, lv[k], li[k]);
        }
        #pragma unroll
        for (int off = 32; off > 0; off >>= 1) {
            float ov = __shfl_xor(bv, off, 64);
            int   oi = __shfl_xor(bi, off, 64);
            better(bv, bi, ov, oi);
        }
        if (lane == 0) {
            cand_v[gw * KWIN + r] = bv;
            cand_i[gw * KWIN + r] = bi;
        }
        #pragma unroll
        for (int k = 0; k < 4; ++k) {
            if (li[k] == bi) li[k] = -1;     // winner out of next rounds
        }
    }
}

// ---------- dispatch 2: single-pass merge via strictly-ordered u64 keys ----------
// key = sortable(v)<<32 | ~index -> max key == (largest v, then smallest index),
// exactly the lax.top_k tie-break. Indices are globally unique so keys are
// strictly ordered: round-r exclusion is simply key < previous winner.
#define MAXC 10   // supports up to 10*256 = 2560 candidates (we have 2500)

__global__ void merge_top5(const float* __restrict__ cand_v,
                           const int* __restrict__ cand_i,
                           int n_cand,
                           float* __restrict__ out) {
    __shared__ unsigned long long swk[4];   // per-wave round winner

    const int tid  = threadIdx.x;           // 256 threads
    const int wave = tid >> 6;
    const int lane = tid & 63;

    unsigned long long k0 = 0ULL, k1 = 0ULL, k2 = 0ULL, k3 = 0ULL, k4 = 0ULL;
    unsigned long long k5 = 0ULL, k6 = 0ULL, k7 = 0ULL, k8 = 0ULL, k9 = 0ULL;
    #pragma unroll
    for (int s = 0; s < MAXC; ++s) {
        int j = s * 256 + tid;
        unsigned long long key = 0ULL;
        if (j < n_cand) {
            int ci = cand_i[j];
            if (ci >= 0 && ci != INT_MAX) {
                unsigned b  = __float_as_uint(cand_v[j]);
                unsigned sv = (b & 0x80000000u) ? ~b : (b | 0x80000000u);
                key = ((unsigned long long)sv << 32) | (unsigned)(~(unsigned)ci);
            }
        }
        if (s == 0) k0 = key; else if (s == 1) k1 = key;
        else if (s == 2) k2 = key; else if (s == 3) k3 = key;
        else if (s == 4) k4 = key; else if (s == 5) k5 = key;
        else if (s == 6) k6 = key; else if (s == 7) k7 = key;
        else if (s == 8) k8 = key; else k9 = key;
    }

    unsigned long long thresh = ~0ULL;      // round 0: everything participates
    for (int r = 0; r < KWIN; ++r) {
        unsigned long long best = 0ULL;
        if (k0 < thresh && k0 > best) best = k0;
        if (k1 < thresh && k1 > best) best = k1;
        if (k2 < thresh && k2 > best) best = k2;
        if (k3 < thresh && k3 > best) best = k3;
        if (k4 < thresh && k4 > best) best = k4;
        if (k5 < thresh && k5 > best) best = k5;
        if (k6 < thresh && k6 > best) best = k6;
        if (k7 < thresh && k7 > best) best = k7;
        if (k8 < thresh && k8 > best) best = k8;
        if (k9 < thresh && k9 > best) best = k9;

        // 64-lane butterfly max (u64 via two 32-bit shuffles)
        #pragma unroll
        for (int off = 32; off > 0; off >>= 1) {
            unsigned hi = (unsigned)(best >> 32);
            unsigned lo = (unsigned)(best & 0xFFFFFFFFu);
            unsigned ohi = __shfl_xor(hi, off, 64);
            unsigned olo = __shfl_xor(lo, off, 64);
            unsigned long long ok = ((unsigned long long)ohi << 32) | olo;
            if (ok > best) best = ok;
        }
        if (lane == 0) swk[wave] = best;
        __syncthreads();

        unsigned long long bb = swk[0];
        if (swk[1] > bb) bb = swk[1];
        if (swk[2] > bb) bb = swk[2];
        if (swk[3] > bb) bb = swk[3];
        __syncthreads();                    // swk reused next round

        if (tid == 0 && bb != 0ULL) {
            unsigned inv = (unsigned)(bb & 0xFFFFFFFFu);
            int idx = (int)(~inv);
            out[idx] = GAIN_UP;
        }
        thresh = bb;                        // next round: strictly below this
    }
}

extern "C" void kernel_launch(void* const* d_in, const int* in_sizes, int n_in,
                              void* d_out, int out_size, void* d_ws, size_t ws_size,
                              hipStream_t stream) {
    const int*   tok = (const int*)d_in[0];
    const float* v0  = (const float*)d_in[1];
    int n     = in_sizes[0];      // 8192
    int vocab = in_sizes[1];      // 128000
    float* out = (float*)d_out;

    int nb     = (vocab + SLICE - 1) / SLICE;   // 125 blocks
    int nwaves = nb * (NT / 64);                // 500 candidate-producing waves

    // ws: cand_v[nwaves*5] f32 | cand_i[nwaves*5] i32
    float* cand_v = (float*)d_ws;
    int*   cand_i = (int*)(cand_v + (size_t)nwaves * KWIN);

    fused_local<<<nb, NT, 0, stream>>>(tok, v0, n, vocab, out, cand_v, cand_i);
    merge_top5<<<1, NT, 0, stream>>>(cand_v, cand_i, nwaves * KWIN, out);
}